// Round 5
// baseline (185.822 us; speedup 1.0000x reference)
//
#include <hip/hip_runtime.h>

// Problem constants: B=4, T=512, U=100, D=512, C=1024
constexpr int B_ = 4;
constexpr int T_ = 512;
constexpr int U_ = 100;
constexpr int D_ = 512;
constexpr int C_ = 1024;

typedef short  s16x8 __attribute__((ext_vector_type(8)));
typedef float  f32x4 __attribute__((ext_vector_type(4)));
typedef unsigned short u16x8 __attribute__((ext_vector_type(8)));

// fp32 -> bf16 RNE (finite inputs; no NaN handling needed)
__device__ __forceinline__ unsigned short f2bf(float f) {
    unsigned int u = __float_as_uint(f);
    return (unsigned short)((u + 0x7FFFu + ((u >> 16) & 1u)) >> 16);
}

// ---------------------------------------------------------------------------
// Fused projections via bf16 MFMA (unchanged: passed, absmax 0.031).
// P[m,c] = sum_d A[m,d] * W[c, woff+d].  grid.y 0..15 -> enc, 16..19 -> dec.
// 128x128 tile, BK=32, 4 waves (2x2), 64x64 per wave = 4x4 fragments.
// ---------------------------------------------------------------------------
__global__ __launch_bounds__(256) void proj_gemm_mfma(
    const float* __restrict__ enc, const float* __restrict__ dec,
    const float* __restrict__ W, float* __restrict__ ep, float* __restrict__ dp)
{
    constexpr int BK  = 32;
    constexpr int LDK = 40;                 // 32 + 8 pad (80 B pitch)
    __shared__ unsigned short As[128 * LDK];
    __shared__ unsigned short Bs[128 * LDK];

    const int by = blockIdx.y;
    const bool is_enc = (by < 16);
    const float* __restrict__ A = is_enc ? enc : dec;
    float* __restrict__ P       = is_enc ? ep : dp;
    const int M    = is_enc ? (B_ * T_) : (B_ * U_);
    const int m0   = (is_enc ? by : (by - 16)) * 128;
    const int woff = is_enc ? 0 : D_;
    const int bn   = blockIdx.x * 128;

    const int tid  = threadIdx.x;
    const int lane = tid & 63;
    const int w    = tid >> 6;
    const int wm   = w >> 1;
    const int wn   = w & 1;
    const int lr   = lane & 15;
    const int lk   = lane >> 4;

    const int srow  = tid >> 1;
    const int shalf = tid & 1;

    f32x4 acc[4][4] = {};

    const float* __restrict__ aBase = A + (size_t)(m0 + srow) * D_ + shalf * 16;
    const float* __restrict__ wBase = W + (size_t)(bn + srow) * (2 * D_) + woff + shalf * 16;
    const bool arow_ok = (m0 + srow) < M;

    for (int kt = 0; kt < D_ / BK; ++kt) {
        if (kt) __syncthreads();
        const int k0 = kt * BK;

        {
            u16x8 v0 = {}, v1 = {};
            if (arow_ok) {
                const float4 f0 = *reinterpret_cast<const float4*>(aBase + k0 + 0);
                const float4 f1 = *reinterpret_cast<const float4*>(aBase + k0 + 4);
                const float4 f2 = *reinterpret_cast<const float4*>(aBase + k0 + 8);
                const float4 f3 = *reinterpret_cast<const float4*>(aBase + k0 + 12);
                v0 = u16x8{f2bf(f0.x), f2bf(f0.y), f2bf(f0.z), f2bf(f0.w),
                           f2bf(f1.x), f2bf(f1.y), f2bf(f1.z), f2bf(f1.w)};
                v1 = u16x8{f2bf(f2.x), f2bf(f2.y), f2bf(f2.z), f2bf(f2.w),
                           f2bf(f3.x), f2bf(f3.y), f2bf(f3.z), f2bf(f3.w)};
            }
            unsigned short* d = &As[srow * LDK + shalf * 16];
            *reinterpret_cast<u16x8*>(d)     = v0;
            *reinterpret_cast<u16x8*>(d + 8) = v1;
        }
        {
            const float4 f0 = *reinterpret_cast<const float4*>(wBase + k0 + 0);
            const float4 f1 = *reinterpret_cast<const float4*>(wBase + k0 + 4);
            const float4 f2 = *reinterpret_cast<const float4*>(wBase + k0 + 8);
            const float4 f3 = *reinterpret_cast<const float4*>(wBase + k0 + 12);
            const u16x8 v0 = {f2bf(f0.x), f2bf(f0.y), f2bf(f0.z), f2bf(f0.w),
                              f2bf(f1.x), f2bf(f1.y), f2bf(f1.z), f2bf(f1.w)};
            const u16x8 v1 = {f2bf(f2.x), f2bf(f2.y), f2bf(f2.z), f2bf(f2.w),
                              f2bf(f3.x), f2bf(f3.y), f2bf(f3.z), f2bf(f3.w)};
            unsigned short* d = &Bs[srow * LDK + shalf * 16];
            *reinterpret_cast<u16x8*>(d)     = v0;
            *reinterpret_cast<u16x8*>(d + 8) = v1;
        }
        __syncthreads();

        s16x8 afrag[4];
        #pragma unroll
        for (int fm = 0; fm < 4; ++fm)
            afrag[fm] = *reinterpret_cast<const s16x8*>(
                &As[(wm * 64 + fm * 16 + lr) * LDK + lk * 8]);
        #pragma unroll
        for (int fn = 0; fn < 4; ++fn) {
            const s16x8 bfrag = *reinterpret_cast<const s16x8*>(
                &Bs[(wn * 64 + fn * 16 + lr) * LDK + lk * 8]);
            #pragma unroll
            for (int fm = 0; fm < 4; ++fm)
                acc[fm][fn] = __builtin_amdgcn_mfma_f32_16x16x32_bf16(
                    afrag[fm], bfrag, acc[fm][fn], 0, 0, 0);
        }
    }

    #pragma unroll
    for (int fm = 0; fm < 4; ++fm) {
        #pragma unroll
        for (int r = 0; r < 4; ++r) {
            const int gm = m0 + wm * 64 + fm * 16 + lk * 4 + r;
            if (gm < M) {
                #pragma unroll
                for (int fn = 0; fn < 4; ++fn) {
                    const int c = bn + wn * 64 + fn * 16 + lr;
                    P[(size_t)gm * C_ + c] = acc[fm][fn][r];
                }
            }
        }
    }
}

// ---------------------------------------------------------------------------
// Phase 2, 2D register tile: block = (8 bt) x (10 u) x full C.
// Per thread (owns 4 consecutive c's): load 8 ep + 10 dp f32x4 into regs
// (72 KB/block read), write 80 f32x4 (320 KB/block) — read demand 0.22x of
// writes, so PLAIN stores (full-line write-combine through L2, like the
// 6.7 TB/s fill kernel) are safe: even 100% dp/ep HBM miss adds only
// ~110 MB (+16 us). Chunked XCD swizzle keeps each XCD's ep/dp slice local;
// the 10 u-tiles of one bt-tile are lbid-adjacent -> concurrent ep reuse.
// ---------------------------------------------------------------------------
constexpr int TT_ = 8;    // bt rows per block (T_ % TT_ == 0 -> no b crossing)
constexpr int UU_ = 10;   // u's per block
constexpr int UTILES_ = U_ / UU_;                 // 10
constexpr int NBLK2 = (B_ * T_ / TT_) * UTILES_;  // 2560, divisible by 8
constexpr int NXCD = 8;

__global__ __launch_bounds__(256) void bcast_add2d(
    const float* __restrict__ ep, const float* __restrict__ dp,
    float* __restrict__ out)
{
    const int bid  = blockIdx.x;
    // chunked XCD swizzle (bijective: NBLK2 % 8 == 0)
    const int lbid = (bid & (NXCD - 1)) * (NBLK2 / NXCD) + (bid >> 3);

    const int btile = lbid / UTILES_;
    const int utile = lbid % UTILES_;
    const int bt0 = btile * TT_;
    const int u0  = utile * UU_;
    const int b   = bt0 / T_;

    const int coff = threadIdx.x * 4;

    // gather rows into registers (all loads independent -> in flight together)
    f32x4 e[TT_], d[UU_];
    #pragma unroll
    for (int i = 0; i < TT_; ++i)
        e[i] = *reinterpret_cast<const f32x4*>(&ep[(size_t)(bt0 + i) * C_ + coff]);
    #pragma unroll
    for (int j = 0; j < UU_; ++j)
        d[j] = *reinterpret_cast<const f32x4*>(&dp[(size_t)(b * U_ + u0 + j) * C_ + coff]);

    // write 8x10 output rows; j-inner -> 40 KB contiguous per i
    #pragma unroll
    for (int i = 0; i < TT_; ++i) {
        float* outp = out + ((size_t)(bt0 + i) * U_ + u0) * C_ + coff;
        #pragma unroll
        for (int j = 0; j < UU_; ++j) {
            const f32x4 r = e[i] + d[j];
            *reinterpret_cast<f32x4*>(outp + (size_t)j * C_) = r;
        }
    }
}

extern "C" void kernel_launch(void* const* d_in, const int* in_sizes, int n_in,
                              void* d_out, int out_size, void* d_ws, size_t ws_size,
                              hipStream_t stream)
{
    const float* enc = (const float*)d_in[0];   // (B, T, D)
    const float* dec = (const float*)d_in[1];   // (B, U, D)
    const float* W   = (const float*)d_in[2];   // (C, 2D)
    float* out = (float*)d_out;                 // (B, T, U, C) fp32

    const int Menc = B_ * T_;   // 2048
    const int Mdec = B_ * U_;   // 400

    const size_t need = (size_t)(Menc + Mdec) * C_ * sizeof(float);  // ~9.6 MB
    if (ws_size < need) return;

    float* ep = (float*)d_ws;
    float* dp = ep + (size_t)Menc * C_;

    // Phase 1: both projections in ONE launch (enc: by 0..15, dec: by 16..19)
    proj_gemm_mfma<<<dim3(C_ / 128, 20), 256, 0, stream>>>(enc, dec, W, ep, dp);

    // Phase 2: broadcast add (HBM write-bound bulk), 2D tile + XCD swizzle
    bcast_add2d<<<NBLK2, 256, 0, stream>>>(ep, dp, out);
}